// Round 13
// baseline (1410.845 us; speedup 1.0000x reference)
//
#include <hip/hip_runtime.h>

#define TT 512
#define BB 32
#define KK 15
#define PGD 8   // register prefetch pipeline depth (steps)

typedef __attribute__((ext_vector_type(8))) short short8;
typedef __attribute__((ext_vector_type(4))) float f32x4;
typedef __attribute__((ext_vector_type(8))) unsigned short us8;
typedef __attribute__((ext_vector_type(4))) unsigned short us4;
typedef __attribute__((ext_vector_type(2))) unsigned int u32x2;

__device__ __forceinline__ float bf2f(unsigned short u){
  union { unsigned int i; float f; } v; v.i = ((unsigned int)u) << 16; return v.f;
}
__device__ __forceinline__ unsigned short f2bf(float f){
  union { float f; unsigned int i; } v; v.f = f;
  return (unsigned short)((v.i + 0x7fffu + ((v.i >> 16) & 1u)) >> 16);
}
__device__ __forceinline__ float bflo(unsigned int u){ return __int_as_float((int)(u << 16)); }
__device__ __forceinline__ float bfhi(unsigned int u){ return __int_as_float((int)(u & 0xffff0000u)); }

__device__ __forceinline__ unsigned short lstm_act(u32x2 gvp, u32x2 pgp, float& cst){
  const float L2E = 1.4426950408889634f;
  float ai = bflo(gvp.x) + bflo(pgp.x);
  float af = bfhi(gvp.x) + bfhi(pgp.x);
  float ag = bflo(gvp.y) + bflo(pgp.y);
  float ao = bfhi(gvp.y) + bfhi(pgp.y);
  float si = __builtin_amdgcn_rcpf(1.f + __builtin_amdgcn_exp2f(-ai*L2E));
  float sf = __builtin_amdgcn_rcpf(1.f + __builtin_amdgcn_exp2f(-af*L2E));
  float tg = 1.f - 2.f*__builtin_amdgcn_rcpf(1.f + __builtin_amdgcn_exp2f(ag*(2.f*L2E)));
  float so = __builtin_amdgcn_rcpf(1.f + __builtin_amdgcn_exp2f(-ao*L2E));
  cst = sf*cst + si*tg;
  float th = 1.f - 2.f*__builtin_amdgcn_rcpf(1.f + __builtin_amdgcn_exp2f(cst*(2.f*L2E)));
  return f2bf(so*th);
}

// ---------- fused prep (f32->bf16 weights, bias) + embedding gather ----------
__global__ void k_prep_embed(const float* __restrict__ wih, const float* __restrict__ whh,
                       const float* __restrict__ bih, const float* __restrict__ bhh,
                       const float* __restrict__ fcw,
                       unsigned short* __restrict__ wih_bf, unsigned short* __restrict__ whh_bf,
                       float* __restrict__ bias, unsigned short* __restrict__ fcw_bf,
                       const int* __restrict__ cid, const int* __restrict__ wid,
                       const float* __restrict__ cemb, const float* __restrict__ wemb,
                       unsigned short* __restrict__ x){
  int bx = blockIdx.x, tid = threadIdx.x;
  if (bx < 2048){
    int i = bx * 256 + tid;
    if (i < 2*2*512*256) wih_bf[i] = f2bf(wih[i]);
    if (i < 2*2*512*128) whh_bf[i] = f2bf(whh[i]);
    if (i < 2*2*512)     bias[i]   = bih[i] + bhh[i];
    if (i < 16*256)      fcw_bf[i] = (i < 15*256) ? f2bf(fcw[i]) : (unsigned short)0;
  } else {
    int m = (bx - 2048)*2 + (tid >> 7);     // two rows per block
    int d = tid & 127;
    int t = m >> 5, b = m & 31;
    int c = cid[b*TT + t], w = wid[b*TT + t];
    x[(size_t)m*256 + d]       = f2bf(cemb[c*128 + d]);
    x[(size_t)m*256 + 128 + d] = f2bf(wemb[(size_t)w*128 + d]);
  }
}

// ---------- input GEMM: pre = x @ wih^T + bias ----------
__global__ __launch_bounds__(256) void k_gemm_pre(const unsigned short* __restrict__ x,
                        const unsigned short* __restrict__ wih_bf,   // layer base (1024,256)
                        const float* __restrict__ bias,              // layer base (1024)
                        unsigned short* __restrict__ pre){
  int lane = threadIdx.x & 63, wv = threadIdx.x >> 6;
  int m0 = blockIdx.x * 128 + wv * 32;      // one t per wave
  int t = m0 >> 5;
  int by = blockIdx.y;                      // = w (hcol block)
  int r16 = lane & 15, q4 = lane >> 4;
  const unsigned short* arow0 = x + (size_t)(m0 + r16)*256 + q4*8;
  const unsigned short* arow1 = arow0 + 16*256;
  short8 a0[8], a1[8];
  #pragma unroll
  for (int ks = 0; ks < 8; ++ks){ a0[ks] = *(const short8*)(arow0 + ks*32);
                                  a1[ks] = *(const short8*)(arow1 + ks*32); }
  f32x4 acc0[8], acc1[8];
  float bs[8];
  #pragma unroll
  for (int sub = 0; sub < 8; ++sub){
    int dir = sub >> 2, g = sub & 3;
    int n0 = dir*512 + g*128 + by*16;
    const unsigned short* brow = wih_bf + (size_t)(n0 + r16)*256 + q4*8;
    f32x4 z0 = {0.f,0.f,0.f,0.f}, z1 = {0.f,0.f,0.f,0.f};
    #pragma unroll
    for (int ks = 0; ks < 8; ++ks){
      short8 bfr = *(const short8*)(brow + ks*32);
      z0 = __builtin_amdgcn_mfma_f32_16x16x32_bf16(a0[ks], bfr, z0, 0, 0, 0);
      z1 = __builtin_amdgcn_mfma_f32_16x16x32_bf16(a1[ks], bfr, z1, 0, 0, 0);
    }
    acc0[sub] = z0; acc1[sub] = z1;
    bs[sub] = bias[n0 + r16];
  }
  #pragma unroll
  for (int dir = 0; dir < 2; ++dir){
    size_t pb0 = ((((size_t)dir*TT + t)*8 + q4)*8 + by)*256;       // half0: group=q4
    size_t pb1 = ((((size_t)dir*TT + t)*8 + 4 + q4)*8 + by)*256;   // half1: group=4+q4
    #pragma unroll
    for (int rr = 0; rr < 4; ++rr){
      us4 s0, s1;
      #pragma unroll
      for (int g = 0; g < 4; ++g){
        s0[g] = f2bf(acc0[dir*4+g][rr] + bs[dir*4+g]);
        s1[g] = f2bf(acc1[dir*4+g][rr] + bs[dir*4+g]);
      }
      *(us4*)(pre + pb0 + (size_t)((r16*4 + rr)*4)) = s0;
      *(us4*)(pre + pb1 + (size_t)((r16*4 + rr)*4)) = s1;
    }
  }
}

// ---------- recurrent LSTM scan: 8 blocks = {dir(2)} x {batch-PAIR (4)} ----------
// DUAL-CHAIN: each block advances TWO independent batch-groups (A,B) per barrier.
// Within-wave ILP across the two chains fills the serial-chain stalls (R11 evidence:
// chain-stall-bound). afrag shared (same dir). 8 waves; bf16-packed spread; 8-deep
// register pg pipelines (pgA/pgB); one raw barrier per super-step.
__global__ __launch_bounds__(512) void k_lstm(const unsigned short* __restrict__ pre,
                                              const unsigned short* __restrict__ whh_bf, // layer base (2,512,128)
                                              unsigned short* __restrict__ y){
  const int dir = blockIdx.x >> 2, bp = blockIdx.x & 3;
  const int gA = bp*2, gB = gA + 1;
  const int tid = threadIdx.x, lane = tid & 63, w = tid >> 6;
  const int r16 = lane & 15, q4 = lane >> 4;
  __shared__ __align__(16) unsigned char hbuf[4096];        // A: p@0/1024, B: p@2048/3072
  __shared__ __align__(16) unsigned char scratch[16384];    // A: w*1024, B: 8192+w*1024
  *(unsigned long long*)(hbuf + tid*8) = 0ull;              // 512*8 = 4096

  // Whh fragments, gate-interleaved rows (shared by both groups)
  short8 afrag[4][4];
  const unsigned short* whhd = whh_bf + (size_t)dir*512*128;
  #pragma unroll
  for (int j = 0; j < 4; ++j){
    int wrow = (r16 & 3)*128 + w*16 + j*4 + (r16 >> 2);
    #pragma unroll
    for (int ks = 0; ks < 4; ++ks)
      afrag[j][ks] = *(const short8*)(whhd + (size_t)wrow*128 + ks*32 + q4*8);
  }

  // pg register prefetch pipelines
  const int t0 = dir ? TT-1 : 0;
  const ptrdiff_t ts = dir ? -16384 : 16384;   // elements per t step (8*8*256)
  const unsigned short* gbaseA = pre + ((((size_t)dir*TT + t0)*8 + gA)*8 + w)*256 + lane*4;
  u32x2 pgA[PGD], pgB[PGD];
  #pragma unroll
  for (int s = 0; s < PGD; ++s){
    pgA[s] = *(const u32x2*)(gbaseA + s*ts);
    pgB[s] = *(const u32x2*)(gbaseA + 2048 + s*ts);
  }
  const unsigned short* gptr = gbaseA + PGD*ts;

  // precomputed LDS addresses
  const unsigned sw = (unsigned)(r16 << 5);     // swizzle (valid lanes r16<4)
  const unsigned char* hbA = hbuf + r16*256;    // A base (p at +0/+1024)
  const unsigned bo0 = (  0u + q4*16) ^ sw, bo1 = ( 64u + q4*16) ^ sw,
                 bo2 = (128u + q4*16) ^ sw, bo3 = (192u + q4*16) ^ sw;
  const unsigned scwA_off = (unsigned)(size_t)(__attribute__((address_space(3))) unsigned char*)
                            (scratch + w*1024 + q4*32 + r16*8);
  const unsigned scwB_off = scwA_off + 8192;
  const unsigned char* scrA = scratch + w*1024 + (size_t)lane*8;
  const int hc = w*16 + (lane >> 2), bbn = lane & 3;
  unsigned char* hwpA = hbuf + bbn*256 + (((unsigned)(hc*2)) ^ (bbn << 5));
  const bool act4 = (r16 < 4);
  const int ws4 = w & 3;
  const ptrdiff_t tsy = dir ? -(BB*256) : (BB*256);
  // each wave stores y for exactly one group: w<4 -> A (slice ws4), w>=4 -> B (slice ws4)
  unsigned short* ysptr = y + ((size_t)t0*BB + (w < 4 ? gA : gB)*4 + r16)*256
                            + dir*128 + ws4*32 + q4*8 - tsy;
  float cstA = 0.f, cstB = 0.f;
  short8 bfA0 = {}, bfA1 = {}, bfA2 = {}, bfA3 = {};
  short8 bfB0 = {}, bfB1 = {}, bfB2 = {}, bfB3 = {};

  __syncthreads();   // hbuf zero visible (also drains prologue loads, one-time)

  for (int it = 0; it < TT/PGD; ++it){
    #pragma unroll
    for (int bd = 0; bd < PGD; ++bd){
      const int p = bd & 1;
      // B-frags for both chains; 16 active lanes
      if (act4){
        bfA0 = *(const short8*)(hbA + p*1024 + bo0);
        bfA1 = *(const short8*)(hbA + p*1024 + bo1);
        bfA2 = *(const short8*)(hbA + p*1024 + bo2);
        bfA3 = *(const short8*)(hbA + p*1024 + bo3);
        bfB0 = *(const short8*)(hbA + 2048 + p*1024 + bo0);
        bfB1 = *(const short8*)(hbA + 2048 + p*1024 + bo1);
        bfB2 = *(const short8*)(hbA + 2048 + p*1024 + bo2);
        bfB3 = *(const short8*)(hbA + 2048 + p*1024 + bo3);
      }
      f32x4 accA[4], accB[4];
      #pragma unroll
      for (int j = 0; j < 4; ++j){
        f32x4 za = {0.f,0.f,0.f,0.f}, zb = {0.f,0.f,0.f,0.f};
        za = __builtin_amdgcn_mfma_f32_16x16x32_bf16(afrag[j][0], bfA0, za, 0, 0, 0);
        za = __builtin_amdgcn_mfma_f32_16x16x32_bf16(afrag[j][1], bfA1, za, 0, 0, 0);
        za = __builtin_amdgcn_mfma_f32_16x16x32_bf16(afrag[j][2], bfA2, za, 0, 0, 0);
        za = __builtin_amdgcn_mfma_f32_16x16x32_bf16(afrag[j][3], bfA3, za, 0, 0, 0);
        zb = __builtin_amdgcn_mfma_f32_16x16x32_bf16(afrag[j][0], bfB0, zb, 0, 0, 0);
        zb = __builtin_amdgcn_mfma_f32_16x16x32_bf16(afrag[j][1], bfB1, zb, 0, 0, 0);
        zb = __builtin_amdgcn_mfma_f32_16x16x32_bf16(afrag[j][2], bfB2, zb, 0, 0, 0);
        zb = __builtin_amdgcn_mfma_f32_16x16x32_bf16(afrag[j][3], bfB3, zb, 0, 0, 0);
        accA[j] = za; accB[j] = zb;
      }
      // y-store of h(t-1): wave w<4 stores A slice ws4, w>=4 stores B slice ws4
      if ((it + bd) != 0 && act4){
        short8 hv;
        if (w < 4) hv = (ws4==0) ? bfA0 : (ws4==1) ? bfA1 : (ws4==2) ? bfA2 : bfA3;
        else       hv = (ws4==0) ? bfB0 : (ws4==1) ? bfB1 : (ws4==2) ? bfB2 : bfB3;
        *(short8*)ysptr = hv;
      }
      ysptr += tsy;
      // packed spreads: cvt_pk -> bf16 quads, 2x ds_write2_b64 per group
      if (act4){
        u32x2 pa0, pa1, pa2, pa3, pb0, pb1, pb2, pb3;
        asm("v_cvt_pk_bf16_f32 %0, %1, %2" : "=v"(pa0.x) : "v"(accA[0][0]), "v"(accA[0][1]));
        asm("v_cvt_pk_bf16_f32 %0, %1, %2" : "=v"(pa0.y) : "v"(accA[0][2]), "v"(accA[0][3]));
        asm("v_cvt_pk_bf16_f32 %0, %1, %2" : "=v"(pa1.x) : "v"(accA[1][0]), "v"(accA[1][1]));
        asm("v_cvt_pk_bf16_f32 %0, %1, %2" : "=v"(pa1.y) : "v"(accA[1][2]), "v"(accA[1][3]));
        asm("v_cvt_pk_bf16_f32 %0, %1, %2" : "=v"(pa2.x) : "v"(accA[2][0]), "v"(accA[2][1]));
        asm("v_cvt_pk_bf16_f32 %0, %1, %2" : "=v"(pa2.y) : "v"(accA[2][2]), "v"(accA[2][3]));
        asm("v_cvt_pk_bf16_f32 %0, %1, %2" : "=v"(pa3.x) : "v"(accA[3][0]), "v"(accA[3][1]));
        asm("v_cvt_pk_bf16_f32 %0, %1, %2" : "=v"(pa3.y) : "v"(accA[3][2]), "v"(accA[3][3]));
        asm("v_cvt_pk_bf16_f32 %0, %1, %2" : "=v"(pb0.x) : "v"(accB[0][0]), "v"(accB[0][1]));
        asm("v_cvt_pk_bf16_f32 %0, %1, %2" : "=v"(pb0.y) : "v"(accB[0][2]), "v"(accB[0][3]));
        asm("v_cvt_pk_bf16_f32 %0, %1, %2" : "=v"(pb1.x) : "v"(accB[1][0]), "v"(accB[1][1]));
        asm("v_cvt_pk_bf16_f32 %0, %1, %2" : "=v"(pb1.y) : "v"(accB[1][2]), "v"(accB[1][3]));
        asm("v_cvt_pk_bf16_f32 %0, %1, %2" : "=v"(pb2.x) : "v"(accB[2][0]), "v"(accB[2][1]));
        asm("v_cvt_pk_bf16_f32 %0, %1, %2" : "=v"(pb2.y) : "v"(accB[2][2]), "v"(accB[2][3]));
        asm("v_cvt_pk_bf16_f32 %0, %1, %2" : "=v"(pb3.x) : "v"(accB[3][0]), "v"(accB[3][1]));
        asm("v_cvt_pk_bf16_f32 %0, %1, %2" : "=v"(pb3.y) : "v"(accB[3][2]), "v"(accB[3][3]));
        asm volatile("ds_write2_b64 %0, %1, %2 offset0:0 offset1:16"
                     :: "v"(scwA_off), "v"(pa0), "v"(pa1) : "memory");
        asm volatile("ds_write2_b64 %0, %1, %2 offset0:32 offset1:48"
                     :: "v"(scwA_off), "v"(pa2), "v"(pa3) : "memory");
        asm volatile("ds_write2_b64 %0, %1, %2 offset0:0 offset1:16"
                     :: "v"(scwB_off), "v"(pb0), "v"(pb1) : "memory");
        asm volatile("ds_write2_b64 %0, %1, %2 offset0:32 offset1:48"
                     :: "v"(scwB_off), "v"(pb2), "v"(pb3) : "memory");
      }
      u32x2 gvA = *(const u32x2*)scrA;            // same-wave in-order LDS
      u32x2 gvB = *(const u32x2*)(scrA + 8192);
      u32x2 pga = pgA[bd], pgb = pgB[bd];         // counted vmcnt via static regs
      pgA[bd] = *(const u32x2*)gptr;              // refill for step+PGD
      pgB[bd] = *(const u32x2*)(gptr + 2048);
      gptr += ts;
      // one activation per lane per chain
      unsigned short hA = lstm_act(gvA, pga, cstA);
      unsigned short hB = lstm_act(gvB, pgb, cstB);
      *(unsigned short*)(hwpA + (p^1)*1024) = hA;
      *(unsigned short*)(hwpA + 2048 + (p^1)*1024) = hB;
      asm volatile("s_waitcnt lgkmcnt(0)" ::: "memory");   // h writes + spreads committed
      __builtin_amdgcn_s_barrier();                        // raw: no vmcnt drain
    }
  }
  // tail: final h (in p=0 buffers) -> y[last t]
  if (act4){
    const unsigned char* hbT = (w < 4) ? hbA : (hbA + 2048);
    short8 hv = *(const short8*)(hbT + ((ws4*64 + q4*16) ^ sw));
    *(short8*)ysptr = hv;
  }
}

// ---------- emissions via MFMA: em[m][k] = y[m]·fcw[k] + fcb[k] ----------
__global__ __launch_bounds__(256) void k_emis(const unsigned short* __restrict__ y,
                       const unsigned short* __restrict__ fcw_bf,   // (16,256), row15 = 0
                       const float* __restrict__ fcb, float* __restrict__ em){
  int lane = threadIdx.x & 63, wv = threadIdx.x >> 6;
  int r16 = lane & 15, q4 = lane >> 4;
  int m0 = blockIdx.x * 64 + wv * 16;
  const unsigned short* arow = y + (size_t)(m0 + r16)*256 + q4*8;
  const unsigned short* brow = fcw_bf + (size_t)r16*256 + q4*8;
  f32x4 acc = {0.f,0.f,0.f,0.f};
  #pragma unroll
  for (int ks = 0; ks < 8; ++ks){
    short8 a = *(const short8*)(arow + ks*32);
    short8 b = *(const short8*)(brow + ks*32);
    acc = __builtin_amdgcn_mfma_f32_16x16x32_bf16(a, b, acc, 0, 0, 0);
  }
  if (r16 < 15){
    float bs = fcb[r16];
    #pragma unroll
    for (int rr = 0; rr < 4; ++rr)
      em[(size_t)(m0 + q4*4 + rr)*16 + r16] = acc[rr] + bs;
  }
}

// ---------- CRF denominator: forward algorithm, 8 blocks x 1 wave x 4 batches ----------
__global__ __launch_bounds__(64) void k_crf_den(const float* __restrict__ em,
                    const int* __restrict__ mask, const float* __restrict__ trans,
                    const float* __restrict__ startt, const float* __restrict__ endt,
                    float* __restrict__ dens){
  int lane = threadIdx.x & 63;
  int g = lane >> 4, j = lane & 15;
  int b = blockIdx.x*4 + g;
  int jj = j < 15 ? j : 14;
  const float L2E = 1.4426950408889634f, LN2 = 0.6931471805599453f;
  float tr_j[15];
  #pragma unroll
  for (int i = 0; i < 15; ++i) tr_j[i] = trans[i*15 + jj];
  float alpha = startt[jj] + em[b*16 + jj];
  int pbase = (lane & 48) << 2;
  auto body = [&](float em_t, int mk){
    float v[15];
    int ai = __float_as_int(alpha);
    #pragma unroll
    for (int i = 0; i < 15; ++i)
      v[i] = __int_as_float(__builtin_amdgcn_ds_bpermute(pbase + i*4, ai)) + tr_j[i];
    float mx = v[0];   // shift by v[0]: spread is small, exp2 safe
    float e[15];
    #pragma unroll
    for (int i = 1; i < 15; ++i) e[i] = __builtin_amdgcn_exp2f((v[i]-mx)*L2E);
    float s = 1.f + ((e[1]+(e[2]+e[3])) + ((e[4]+e[5])+(e[6]+e[7])))
            + (((e[8]+e[9])+(e[10]+e[11])) + ((e[12]+e[13])+e[14]));
    float nxt = mx + __builtin_amdgcn_logf(s)*LN2 + em_t;
    alpha = mk ? nxt : alpha;
  };
  float emA = em[((size_t)1*BB + b)*16 + jj], emB = em[((size_t)2*BB + b)*16 + jj];
  int mkA = mask[b*TT + 1], mkB = mask[b*TT + 2];
  for (int t = 1; t + 1 < TT; t += 2){
    int ta = t+2 < TT ? t+2 : TT-1;
    int tb = t+3 < TT ? t+3 : TT-1;
    float emA2 = em[((size_t)ta*BB + b)*16 + jj];
    float emB2 = em[((size_t)tb*BB + b)*16 + jj];
    int mkA2 = mask[b*TT + ta], mkB2 = mask[b*TT + tb];
    body(emA, mkA);
    body(emB, mkB);
    emA = emA2; emB = emB2; mkA = mkA2; mkB = mkB2;
  }
  body(emA, mkA);   // t = TT-1
  float val = (j < 15) ? alpha + endt[j] : -3.0e38f;
  float mx = val;
  #pragma unroll
  for (int off = 8; off; off >>= 1) mx = fmaxf(mx, __shfl_xor(mx, off, 16));
  float ee = (j < 15) ? __builtin_amdgcn_exp2f((val-mx)*L2E) : 0.f;
  #pragma unroll
  for (int off = 8; off; off >>= 1) ee += __shfl_xor(ee, off, 16);
  if (j == 0) dens[b] = mx + __builtin_amdgcn_logf(ee)*LN2;
}

// ---------- CRF final: numerator (parallel over b,t) + combine with dens ----------
__global__ __launch_bounds__(512) void k_crf_fin(const float* __restrict__ em, const int* __restrict__ tags,
                    const int* __restrict__ mask, const float* __restrict__ trans,
                    const float* __restrict__ startt, const float* __restrict__ endt,
                    const float* __restrict__ dens, float* __restrict__ out){
  __shared__ float sh_tr[15][16];
  __shared__ float sh_s[16], sh_e[16];
  __shared__ float red[8];
  __shared__ int seqend[32];
  int tid = threadIdx.x, wv = tid >> 6;
  if (tid < 225) sh_tr[tid/15][tid%15] = trans[tid];
  if (tid < 15){ sh_s[tid] = startt[tid]; sh_e[tid] = endt[tid]; }
  {
    int b2 = tid >> 4, ch = tid & 15;
    int cnt = 0;
    #pragma unroll 4
    for (int t2 = 0; t2 < 32; ++t2) cnt += (mask[b2*TT + ch*32 + t2] != 0) ? 1 : 0;
    #pragma unroll
    for (int off = 8; off; off >>= 1) cnt += __shfl_down(cnt, off, 16);
    if (ch == 0) seqend[b2] = cnt - 1;
  }
  __syncthreads();
  float num = 0.f;
  #pragma unroll 4
  for (int i = tid; i < BB*TT; i += 512){
    int b2 = i >> 9, t = i & (TT-1);
    int tg = tags[b2*TT + t];
    if (t == 0){
      num += sh_s[tg] + em[b2*16 + tg];
    } else if (mask[b2*TT + t] != 0){
      int tp = tags[b2*TT + t - 1];
      num += sh_tr[tp][tg] + em[((size_t)t*BB + b2)*16 + tg];
    }
  }
  if (tid < 32) num += sh_e[tags[tid*TT + seqend[tid]]];
  #pragma unroll
  for (int off = 32; off; off >>= 1) num += __shfl_down(num, off, 64);
  if ((tid & 63) == 0) red[wv] = num;
  __syncthreads();
  if (tid == 0){
    float numtot = 0.f;
    #pragma unroll
    for (int i = 0; i < 8; ++i) numtot += red[i];
    float dentot = 0.f;
    for (int i = 0; i < 32; ++i) dentot += dens[i];
    out[0] = dentot - numtot;   // = -(num - den).sum()
  }
}

extern "C" void kernel_launch(void* const* d_in, const int* in_sizes, int n_in,
                              void* d_out, int out_size, void* d_ws, size_t ws_size,
                              hipStream_t stream){
  const int*   cid  = (const int*)d_in[0];
  const int*   wid  = (const int*)d_in[1];
  const int*   tags = (const int*)d_in[2];
  const int*   mask = (const int*)d_in[3];
  const float* cemb = (const float*)d_in[4];
  const float* wemb = (const float*)d_in[5];
  const float* wih  = (const float*)d_in[6];
  const float* whh  = (const float*)d_in[7];
  const float* bih  = (const float*)d_in[8];
  const float* bhh  = (const float*)d_in[9];
  const float* fcw  = (const float*)d_in[10];
  const float* fcb  = (const float*)d_in[11];
  const float* trans= (const float*)d_in[12];
  const float* st   = (const float*)d_in[13];
  const float* en   = (const float*)d_in[14];

  char* ws = (char*)d_ws;
  size_t off = 0;
  auto alloc = [&](size_t bytes){ size_t o = off; off += (bytes + 255) & ~(size_t)255; return o; };
  unsigned short* wih_bf = (unsigned short*)(ws + alloc((size_t)2*2*512*256*2));
  unsigned short* whh_bf = (unsigned short*)(ws + alloc((size_t)2*2*512*128*2));
  float*          bias   = (float*)         (ws + alloc((size_t)2*2*512*4));
  unsigned short* fcw_bf = (unsigned short*)(ws + alloc((size_t)16*256*2));
  unsigned short* x0     = (unsigned short*)(ws + alloc((size_t)TT*BB*256*2));
  unsigned short* x1     = (unsigned short*)(ws + alloc((size_t)TT*BB*256*2));
  unsigned short* pre    = (unsigned short*)(ws + alloc((size_t)2*TT*BB*512*2));
  float*          em     = (float*)         (ws + alloc((size_t)TT*BB*16*4));
  float*          dens   = (float*)         (ws + alloc((size_t)32*4));

  k_prep_embed<<<2048 + TT*BB/2, 256, 0, stream>>>(wih, whh, bih, bhh, fcw,
                                                   wih_bf, whh_bf, bias, fcw_bf,
                                                   cid, wid, cemb, wemb, x0);
  for (int l = 0; l < 2; ++l){
    const unsigned short* xin = l ? x1 : x0;
    unsigned short* yout = l ? x0 : x1;
    k_gemm_pre<<<dim3(128,8), 256, 0, stream>>>(xin, wih_bf + (size_t)l*2*512*256,
                                                bias + (size_t)l*1024, pre);
    k_lstm<<<8, 512, 0, stream>>>(pre, whh_bf + (size_t)l*2*512*128, yout);
  }
  k_emis<<<256, 256, 0, stream>>>(x0, fcw_bf, fcb, em);
  k_crf_den<<<8, 64, 0, stream>>>(em, mask, trans, st, en, dens);
  k_crf_fin<<<1, 512, 0, stream>>>(em, tags, mask, trans, st, en, dens, (float*)d_out);
}

// Round 14
// 821.228 us; speedup vs baseline: 1.7180x; 1.7180x over previous
//
#include <hip/hip_runtime.h>

#define TT 512
#define BB 32
#define KK 15
#define PGD 8   // register prefetch pipeline depth (steps)

typedef __attribute__((ext_vector_type(8))) short short8;
typedef __attribute__((ext_vector_type(4))) float f32x4;
typedef __attribute__((ext_vector_type(8))) unsigned short us8;
typedef __attribute__((ext_vector_type(4))) unsigned short us4;
typedef __attribute__((ext_vector_type(2))) unsigned int u32x2;

__device__ __forceinline__ float bf2f(unsigned short u){
  union { unsigned int i; float f; } v; v.i = ((unsigned int)u) << 16; return v.f;
}
__device__ __forceinline__ unsigned short f2bf(float f){
  union { float f; unsigned int i; } v; v.f = f;
  return (unsigned short)((v.i + 0x7fffu + ((v.i >> 16) & 1u)) >> 16);
}
__device__ __forceinline__ float bflo(unsigned int u){ return __int_as_float((int)(u << 16)); }
__device__ __forceinline__ float bfhi(unsigned int u){ return __int_as_float((int)(u & 0xffff0000u)); }

// ---------- fused prep (f32->bf16 weights, bias) + embedding gather ----------
__global__ void k_prep_embed(const float* __restrict__ wih, const float* __restrict__ whh,
                       const float* __restrict__ bih, const float* __restrict__ bhh,
                       const float* __restrict__ fcw,
                       unsigned short* __restrict__ wih_bf, unsigned short* __restrict__ whh_bf,
                       float* __restrict__ bias, unsigned short* __restrict__ fcw_bf,
                       const int* __restrict__ cid, const int* __restrict__ wid,
                       const float* __restrict__ cemb, const float* __restrict__ wemb,
                       unsigned short* __restrict__ x){
  int bx = blockIdx.x, tid = threadIdx.x;
  if (bx < 2048){
    int i = bx * 256 + tid;
    if (i < 2*2*512*256) wih_bf[i] = f2bf(wih[i]);
    if (i < 2*2*512*128) whh_bf[i] = f2bf(whh[i]);
    if (i < 2*2*512)     bias[i]   = bih[i] + bhh[i];
    if (i < 16*256)      fcw_bf[i] = (i < 15*256) ? f2bf(fcw[i]) : (unsigned short)0;
  } else {
    int m = (bx - 2048)*2 + (tid >> 7);     // two rows per block
    int d = tid & 127;
    int t = m >> 5, b = m & 31;
    int c = cid[b*TT + t], w = wid[b*TT + t];
    x[(size_t)m*256 + d]       = f2bf(cemb[c*128 + d]);
    x[(size_t)m*256 + 128 + d] = f2bf(wemb[(size_t)w*128 + d]);
  }
}

// ---------- input GEMM: pre = x @ wih^T + bias ----------
__global__ __launch_bounds__(256) void k_gemm_pre(const unsigned short* __restrict__ x,
                        const unsigned short* __restrict__ wih_bf,   // layer base (1024,256)
                        const float* __restrict__ bias,              // layer base (1024)
                        unsigned short* __restrict__ pre){
  int lane = threadIdx.x & 63, wv = threadIdx.x >> 6;
  int m0 = blockIdx.x * 128 + wv * 32;      // one t per wave
  int t = m0 >> 5;
  int by = blockIdx.y;                      // = w (hcol block)
  int r16 = lane & 15, q4 = lane >> 4;
  const unsigned short* arow0 = x + (size_t)(m0 + r16)*256 + q4*8;
  const unsigned short* arow1 = arow0 + 16*256;
  short8 a0[8], a1[8];
  #pragma unroll
  for (int ks = 0; ks < 8; ++ks){ a0[ks] = *(const short8*)(arow0 + ks*32);
                                  a1[ks] = *(const short8*)(arow1 + ks*32); }
  f32x4 acc0[8], acc1[8];
  float bs[8];
  #pragma unroll
  for (int sub = 0; sub < 8; ++sub){
    int dir = sub >> 2, g = sub & 3;
    int n0 = dir*512 + g*128 + by*16;
    const unsigned short* brow = wih_bf + (size_t)(n0 + r16)*256 + q4*8;
    f32x4 z0 = {0.f,0.f,0.f,0.f}, z1 = {0.f,0.f,0.f,0.f};
    #pragma unroll
    for (int ks = 0; ks < 8; ++ks){
      short8 bfr = *(const short8*)(brow + ks*32);
      z0 = __builtin_amdgcn_mfma_f32_16x16x32_bf16(a0[ks], bfr, z0, 0, 0, 0);
      z1 = __builtin_amdgcn_mfma_f32_16x16x32_bf16(a1[ks], bfr, z1, 0, 0, 0);
    }
    acc0[sub] = z0; acc1[sub] = z1;
    bs[sub] = bias[n0 + r16];
  }
  #pragma unroll
  for (int dir = 0; dir < 2; ++dir){
    size_t pb0 = ((((size_t)dir*TT + t)*8 + q4)*8 + by)*256;       // half0: group=q4
    size_t pb1 = ((((size_t)dir*TT + t)*8 + 4 + q4)*8 + by)*256;   // half1: group=4+q4
    #pragma unroll
    for (int rr = 0; rr < 4; ++rr){
      us4 s0, s1;
      #pragma unroll
      for (int g = 0; g < 4; ++g){
        s0[g] = f2bf(acc0[dir*4+g][rr] + bs[dir*4+g]);
        s1[g] = f2bf(acc1[dir*4+g][rr] + bs[dir*4+g]);
      }
      *(us4*)(pre + pb0 + (size_t)((r16*4 + rr)*4)) = s0;
      *(us4*)(pre + pb1 + (size_t)((r16*4 + rr)*4)) = s1;
    }
  }
}

// ---------- recurrent LSTM scan: 16 blocks = {dir(2)} x {batch group of 4 (8)} ----------
// 8 waves / 512 threads (measured optimum across R3-R13 variants). Gate-interleaved
// 4-chain MFMA + bf16-packed spread (2x ds_write2_b64 + ds_read_b64); 8x-unrolled;
// 8-deep register pg pipeline; one raw barrier/step.
__global__ __launch_bounds__(512) void k_lstm(const unsigned short* __restrict__ pre,
                                              const unsigned short* __restrict__ whh_bf, // layer base (2,512,128)
                                              unsigned short* __restrict__ y){
  const int dir = blockIdx.x >> 3, grp = blockIdx.x & 7;
  const int tid = threadIdx.x, lane = tid & 63, w = tid >> 6;
  const int r16 = lane & 15, q4 = lane >> 4;
  __shared__ __align__(16) unsigned char hbuf[2*1024];     // 2 x [4 batch][128 h] bf16, swizzled
  __shared__ __align__(16) unsigned char scratch[8*1024];  // per-wave gate spread (bf16-packed)
  *(unsigned int*)(hbuf + tid*4) = 0u;

  // Whh fragments, gate-interleaved rows: afrag[j] row r16 -> Whh row
  //   (r16&3)*128 + w*16 + j*4 + (r16>>2)
  short8 afrag[4][4];
  const unsigned short* whhd = whh_bf + (size_t)dir*512*128;
  #pragma unroll
  for (int j = 0; j < 4; ++j){
    int wrow = (r16 & 3)*128 + w*16 + j*4 + (r16 >> 2);
    #pragma unroll
    for (int ks = 0; ks < 4; ++ks)
      afrag[j][ks] = *(const short8*)(whhd + (size_t)wrow*128 + ks*32 + q4*8);
  }

  // pg register prefetch pipeline (8B/lane/step, bf16 gate quads)
  const int t0 = dir ? TT-1 : 0;
  const ptrdiff_t ts = dir ? -16384 : 16384;   // elements per t step (8*8*256)
  const unsigned short* gbase = pre + ((((size_t)dir*TT + t0)*8 + grp)*8 + w)*256 + lane*4;
  u32x2 pgbuf[PGD];
  #pragma unroll
  for (int s = 0; s < PGD; ++s) pgbuf[s] = *(const u32x2*)(gbase + s*ts);
  const unsigned short* gptr = gbase + PGD*ts;

  // precomputed LDS addresses
  const unsigned sw = (unsigned)(r16 << 5);     // swizzle (valid lanes r16<4)
  const unsigned char* hb = hbuf + r16*256;
  const unsigned bo0 = (  0u + q4*16) ^ sw, bo1 = ( 64u + q4*16) ^ sw,
                 bo2 = (128u + q4*16) ^ sw, bo3 = (192u + q4*16) ^ sw;
  // spread scratch: layout [hc(16)][b(4)] x 8B per wave; source (q4,r16<4) writes
  // j=0..3 at base + j*128B; target lane reads 8B at lane*8.
  const unsigned scw_off = (unsigned)(size_t)(__attribute__((address_space(3))) unsigned char*)
                           (scratch + w*1024 + q4*32 + r16*8);
  const unsigned char* scr8 = scratch + w*1024 + (size_t)lane*8;
  const int hc = w*16 + (lane >> 2), bbn = lane & 3;
  unsigned char* hwp = hbuf + bbn*256 + (((unsigned)(hc*2)) ^ (bbn << 5));
  const bool act4 = (r16 < 4);
  const bool yw = (w < 4) && act4;
  const ptrdiff_t tsy = dir ? -(BB*256) : (BB*256);
  unsigned short* ysptr = y + ((size_t)t0*BB + grp*4 + r16)*256 + dir*128 + w*32 + q4*8 - tsy;
  const float L2E = 1.4426950408889634f;
  float cst = 0.f;
  short8 bf0 = {}, bf1 = {}, bf2 = {}, bf3 = {};   // masked lanes stay zero forever

  __syncthreads();   // hbuf zero visible (also drains prologue loads, one-time)

  for (int it = 0; it < TT/PGD; ++it){
    #pragma unroll
    for (int bd = 0; bd < PGD; ++bd){
      const int p = bd & 1;
      // B-frag: h(t-1); 16 active lanes
      if (act4){
        bf0 = *(const short8*)(hb + p*1024 + bo0);
        bf1 = *(const short8*)(hb + p*1024 + bo1);
        bf2 = *(const short8*)(hb + p*1024 + bo2);
        bf3 = *(const short8*)(hb + p*1024 + bo3);
      }
      f32x4 acc[4];
      #pragma unroll
      for (int j = 0; j < 4; ++j){
        f32x4 z = {0.f,0.f,0.f,0.f};
        z = __builtin_amdgcn_mfma_f32_16x16x32_bf16(afrag[j][0], bf0, z, 0, 0, 0);
        z = __builtin_amdgcn_mfma_f32_16x16x32_bf16(afrag[j][1], bf1, z, 0, 0, 0);
        z = __builtin_amdgcn_mfma_f32_16x16x32_bf16(afrag[j][2], bf2, z, 0, 0, 0);
        z = __builtin_amdgcn_mfma_f32_16x16x32_bf16(afrag[j][3], bf3, z, 0, 0, 0);
        acc[j] = z;   // lane(q4, r16<4): acc[j][g] = gate g, hcol w*16+j*4+q4, batch r16
      }
      // y-store of h(t-1) from bf regs (waves 0..3 store their ks=w slice)
      if ((it + bd) != 0 && yw){
        short8 hv = (w==0) ? bf0 : (w==1) ? bf1 : (w==2) ? bf2 : bf3;
        *(short8*)ysptr = hv;
      }
      ysptr += tsy;
      // packed spread: cvt_pk acc[j] -> bf16 quads, 2x ds_write2_b64 (4 vecs, 2 LDS ops)
      if (act4){
        u32x2 pk0, pk1, pk2, pk3;
        asm("v_cvt_pk_bf16_f32 %0, %1, %2" : "=v"(pk0.x) : "v"(acc[0][0]), "v"(acc[0][1]));
        asm("v_cvt_pk_bf16_f32 %0, %1, %2" : "=v"(pk0.y) : "v"(acc[0][2]), "v"(acc[0][3]));
        asm("v_cvt_pk_bf16_f32 %0, %1, %2" : "=v"(pk1.x) : "v"(acc[1][0]), "v"(acc[1][1]));
        asm("v_cvt_pk_bf16_f32 %0, %1, %2" : "=v"(pk1.y) : "v"(acc[1][2]), "v"(acc[1][3]));
        asm("v_cvt_pk_bf16_f32 %0, %1, %2" : "=v"(pk2.x) : "v"(acc[2][0]), "v"(acc[2][1]));
        asm("v_cvt_pk_bf16_f32 %0, %1, %2" : "=v"(pk2.y) : "v"(acc[2][2]), "v"(acc[2][3]));
        asm("v_cvt_pk_bf16_f32 %0, %1, %2" : "=v"(pk3.x) : "v"(acc[3][0]), "v"(acc[3][1]));
        asm("v_cvt_pk_bf16_f32 %0, %1, %2" : "=v"(pk3.y) : "v"(acc[3][2]), "v"(acc[3][3]));
        asm volatile("ds_write2_b64 %0, %1, %2 offset0:0 offset1:16"
                     :: "v"(scw_off), "v"(pk0), "v"(pk1) : "memory");
        asm volatile("ds_write2_b64 %0, %1, %2 offset0:32 offset1:48"
                     :: "v"(scw_off), "v"(pk2), "v"(pk3) : "memory");
      }
      u32x2 gvp = *(const u32x2*)scr8;          // ds_read_b64; same-wave in-order LDS
      u32x2 pgp = pgbuf[bd];                    // compiler inserts counted vmcnt
      pgbuf[bd] = *(const u32x2*)gptr;          // refill for step+PGD
      gptr += ts;
      // single activation per lane (bf16 gate inputs)
      float ai = bflo(gvp.x) + bflo(pgp.x);
      float af = bfhi(gvp.x) + bfhi(pgp.x);
      float ag = bflo(gvp.y) + bflo(pgp.y);
      float ao = bfhi(gvp.y) + bfhi(pgp.y);
      float si = __builtin_amdgcn_rcpf(1.f + __builtin_amdgcn_exp2f(-ai*L2E));
      float sf = __builtin_amdgcn_rcpf(1.f + __builtin_amdgcn_exp2f(-af*L2E));
      float tg = 1.f - 2.f*__builtin_amdgcn_rcpf(1.f + __builtin_amdgcn_exp2f(ag*(2.f*L2E)));
      float so = __builtin_amdgcn_rcpf(1.f + __builtin_amdgcn_exp2f(-ao*L2E));
      cst = sf*cst + si*tg;
      float th = 1.f - 2.f*__builtin_amdgcn_rcpf(1.f + __builtin_amdgcn_exp2f(cst*(2.f*L2E)));
      *(unsigned short*)(hwp + (p^1)*1024) = f2bf(so*th);
      asm volatile("s_waitcnt lgkmcnt(0)" ::: "memory");   // h write + spread committed
      __builtin_amdgcn_s_barrier();                        // raw: no vmcnt drain
    }
  }
  // tail: final h (in hbuf[0]) -> y[last t]
  if (yw){
    short8 hv = *(const short8*)(hb + ((w*64 + q4*16) ^ sw));
    *(short8*)ysptr = hv;
  }
}

// ---------- emissions via MFMA: em[m][k] = y[m]·fcw[k] + fcb[k] ----------
__global__ __launch_bounds__(256) void k_emis(const unsigned short* __restrict__ y,
                       const unsigned short* __restrict__ fcw_bf,   // (16,256), row15 = 0
                       const float* __restrict__ fcb, float* __restrict__ em){
  int lane = threadIdx.x & 63, wv = threadIdx.x >> 6;
  int r16 = lane & 15, q4 = lane >> 4;
  int m0 = blockIdx.x * 64 + wv * 16;
  const unsigned short* arow = y + (size_t)(m0 + r16)*256 + q4*8;
  const unsigned short* brow = fcw_bf + (size_t)r16*256 + q4*8;
  f32x4 acc = {0.f,0.f,0.f,0.f};
  #pragma unroll
  for (int ks = 0; ks < 8; ++ks){
    short8 a = *(const short8*)(arow + ks*32);
    short8 b = *(const short8*)(brow + ks*32);
    acc = __builtin_amdgcn_mfma_f32_16x16x32_bf16(a, b, acc, 0, 0, 0);
  }
  if (r16 < 15){
    float bs = fcb[r16];
    #pragma unroll
    for (int rr = 0; rr < 4; ++rr)
      em[(size_t)(m0 + q4*4 + rr)*16 + r16] = acc[rr] + bs;
  }
}

// ---------- CRF denominator: EXP-DOMAIN forward algorithm ----------
// 8 blocks x 1 wave x 4 batches. alpha kept as A = 2^(alpha*L2E - off); transition is
// 15 bpermute + 15 FMA + 1 mul (E = 2^(em*L2E) precomputed off-chain 2 steps ahead).
// Rescale by group-uniform v[0] every 4 steps, accumulating log2 offset `off`.
__global__ __launch_bounds__(64) void k_crf_den(const float* __restrict__ em,
                    const int* __restrict__ mask, const float* __restrict__ trans,
                    const float* __restrict__ startt, const float* __restrict__ endt,
                    float* __restrict__ dens){
  int lane = threadIdx.x & 63;
  int g = lane >> 4, j = lane & 15;
  int b = blockIdx.x*4 + g;
  int jj = j < 15 ? j : 14;
  const float L2E = 1.4426950408889634f, LN2 = 0.6931471805599453f;
  float tr2[15];
  #pragma unroll
  for (int i = 0; i < 15; ++i) tr2[i] = __builtin_amdgcn_exp2f(trans[i*15 + jj]*L2E);
  float A = __builtin_amdgcn_exp2f((startt[jj] + em[b*16 + jj])*L2E);
  float off = 0.f;   // log2 offset, uniform across the 16-lane group
  int pbase = (lane & 48) << 2;
  auto body = [&](float E, int mk, bool resc){
    float v[15];
    int ai = __float_as_int(A);
    #pragma unroll
    for (int i = 0; i < 15; ++i)
      v[i] = __int_as_float(__builtin_amdgcn_ds_bpermute(pbase + i*4, ai));
    float s01 = v[0]*tr2[0] + v[1]*tr2[1];
    float s23 = v[2]*tr2[2] + v[3]*tr2[3];
    float s45 = v[4]*tr2[4] + v[5]*tr2[5];
    float s67 = v[6]*tr2[6] + v[7]*tr2[7];
    float s89 = v[8]*tr2[8] + v[9]*tr2[9];
    float sab = v[10]*tr2[10] + v[11]*tr2[11];
    float scd = v[12]*tr2[12] + v[13]*tr2[13];
    float s = (((s01 + s23) + (s45 + s67)) + ((s89 + sab) + (scd + v[14]*tr2[14])));
    float nxt = s * E;
    A = mk ? nxt : A;
    if (resc){
      float sc = v[0];                              // uniform across group, > 0
      A *= __builtin_amdgcn_rcpf(sc);
      off += __builtin_amdgcn_logf(sc);             // v_log_f32 = log2
    }
  };
  float eA = __builtin_amdgcn_exp2f(em[((size_t)1*BB + b)*16 + jj]*L2E);
  float eB = __builtin_amdgcn_exp2f(em[((size_t)2*BB + b)*16 + jj]*L2E);
  int mkA = mask[b*TT + 1], mkB = mask[b*TT + 2];
  for (int t = 1; t + 1 < TT; t += 2){
    int ta = t+2 < TT ? t+2 : TT-1;
    int tb = t+3 < TT ? t+3 : TT-1;
    float eA2 = __builtin_amdgcn_exp2f(em[((size_t)ta*BB + b)*16 + jj]*L2E);
    float eB2 = __builtin_amdgcn_exp2f(em[((size_t)tb*BB + b)*16 + jj]*L2E);
    int mkA2 = mask[b*TT + ta], mkB2 = mask[b*TT + tb];
    body(eA, mkA, false);
    body(eB, mkB, ((t+1) & 3) == 0);   // rescale every 4 steps
    eA = eA2; eB = eB2; mkA = mkA2; mkB = mkB2;
  }
  body(eA, mkA, false);   // t = TT-1
  // final: val_j = alpha_j + end_j  ->  A_j * 2^(end_j*L2E); logsumexp over j
  float Ae = (j < 15) ? A * __builtin_amdgcn_exp2f(endt[j]*L2E) : 0.f;
  float mx = Ae;
  #pragma unroll
  for (int off2 = 8; off2; off2 >>= 1) mx = fmaxf(mx, __shfl_xor(mx, off2, 16));
  float rm = __builtin_amdgcn_rcpf(mx);
  float ee = Ae * rm;
  #pragma unroll
  for (int off2 = 8; off2; off2 >>= 1) ee += __shfl_xor(ee, off2, 16);
  if (j == 0) dens[b] = (off + __builtin_amdgcn_logf(mx) + __builtin_amdgcn_logf(ee))*LN2;
}

// ---------- CRF final: numerator (parallel over b,t) + combine with dens ----------
__global__ __launch_bounds__(512) void k_crf_fin(const float* __restrict__ em, const int* __restrict__ tags,
                    const int* __restrict__ mask, const float* __restrict__ trans,
                    const float* __restrict__ startt, const float* __restrict__ endt,
                    const float* __restrict__ dens, float* __restrict__ out){
  __shared__ float sh_tr[15][16];
  __shared__ float sh_s[16], sh_e[16];
  __shared__ float red[8];
  __shared__ int seqend[32];
  int tid = threadIdx.x, wv = tid >> 6;
  if (tid < 225) sh_tr[tid/15][tid%15] = trans[tid];
  if (tid < 15){ sh_s[tid] = startt[tid]; sh_e[tid] = endt[tid]; }
  {
    int b2 = tid >> 4, ch = tid & 15;
    int cnt = 0;
    #pragma unroll 4
    for (int t2 = 0; t2 < 32; ++t2) cnt += (mask[b2*TT + ch*32 + t2] != 0) ? 1 : 0;
    #pragma unroll
    for (int off = 8; off; off >>= 1) cnt += __shfl_down(cnt, off, 16);
    if (ch == 0) seqend[b2] = cnt - 1;
  }
  __syncthreads();
  float num = 0.f;
  #pragma unroll 4
  for (int i = tid; i < BB*TT; i += 512){
    int b2 = i >> 9, t = i & (TT-1);
    int tg = tags[b2*TT + t];
    if (t == 0){
      num += sh_s[tg] + em[b2*16 + tg];
    } else if (mask[b2*TT + t] != 0){
      int tp = tags[b2*TT + t - 1];
      num += sh_tr[tp][tg] + em[((size_t)t*BB + b2)*16 + tg];
    }
  }
  if (tid < 32) num += sh_e[tags[tid*TT + seqend[tid]]];
  #pragma unroll
  for (int off = 32; off; off >>= 1) num += __shfl_down(num, off, 64);
  if ((tid & 63) == 0) red[wv] = num;
  __syncthreads();
  if (tid == 0){
    float numtot = 0.f;
    #pragma unroll
    for (int i = 0; i < 8; ++i) numtot += red[i];
    float dentot = 0.f;
    for (int i = 0; i < 32; ++i) dentot += dens[i];
    out[0] = dentot - numtot;   // = -(num - den).sum()
  }
}

extern "C" void kernel_launch(void* const* d_in, const int* in_sizes, int n_in,
                              void* d_out, int out_size, void* d_ws, size_t ws_size,
                              hipStream_t stream){
  const int*   cid  = (const int*)d_in[0];
  const int*   wid  = (const int*)d_in[1];
  const int*   tags = (const int*)d_in[2];
  const int*   mask = (const int*)d_in[3];
  const float* cemb = (const float*)d_in[4];
  const float* wemb = (const float*)d_in[5];
  const float* wih  = (const float*)d_in[6];
  const float* whh  = (const float*)d_in[7];
  const float* bih  = (const float*)d_in[8];
  const float* bhh  = (const float*)d_in[9];
  const float* fcw  = (const float*)d_in[10];
  const float* fcb  = (const float*)d_in[11];
  const float* trans= (const float*)d_in[12];
  const float* st   = (const float*)d_in[13];
  const float* en   = (const float*)d_in[14];

  char* ws = (char*)d_ws;
  size_t off = 0;
  auto alloc = [&](size_t bytes){ size_t o = off; off += (bytes + 255) & ~(size_t)255; return o; };
  unsigned short* wih_bf = (unsigned short*)(ws + alloc((size_t)2*2*512*256*2));
  unsigned short* whh_bf = (unsigned short*)(ws + alloc((size_t)2*2*512*128*2));
  float*          bias   = (float*)         (ws + alloc((size_t)2*2*512*4));
  unsigned short* fcw_bf = (unsigned short*)(ws + alloc((size_t)16*256*2));
  unsigned short* x0     = (unsigned short*)(ws + alloc((size_t)TT*BB*256*2));
  unsigned short* x1     = (unsigned short*)(ws + alloc((size_t)TT*BB*256*2));
  unsigned short* pre    = (unsigned short*)(ws + alloc((size_t)2*TT*BB*512*2));
  float*          em     = (float*)         (ws + alloc((size_t)TT*BB*16*4));
  float*          dens   = (float*)         (ws + alloc((size_t)32*4));

  k_prep_embed<<<2048 + TT*BB/2, 256, 0, stream>>>(wih, whh, bih, bhh, fcw,
                                                   wih_bf, whh_bf, bias, fcw_bf,
                                                   cid, wid, cemb, wemb, x0);
  for (int l = 0; l < 2; ++l){
    const unsigned short* xin = l ? x1 : x0;
    unsigned short* yout = l ? x0 : x1;
    k_gemm_pre<<<dim3(128,8), 256, 0, stream>>>(xin, wih_bf + (size_t)l*2*512*256,
                                                bias + (size_t)l*1024, pre);
    k_lstm<<<16, 512, 0, stream>>>(pre, whh_bf + (size_t)l*2*512*128, yout);
  }
  k_emis<<<256, 256, 0, stream>>>(x0, fcw_bf, fcb, em);
  k_crf_den<<<8, 64, 0, stream>>>(em, mask, trans, st, en, dens);
  k_crf_fin<<<1, 512, 0, stream>>>(em, tags, mask, trans, st, en, dens, (float*)d_out);
}